// Round 1
// baseline (3454.137 us; speedup 1.0000x reference)
//
#include <hip/hip_runtime.h>
#include <cfloat>

// Problem constants (from reference): B=16, N=8192, C=256; M derived from out_size.
#define BB 16
#define NN 8192
#define CC 256
#define NT 512                 // threads per FPS block (8 waves)
#define PPT (NN / NT)          // 16 points per thread, held in registers
#define NWAVES (NT / 64)       // 8

// One workgroup per batch. Points live in registers (px/py/pz[16]); dist[16]
// in registers. Per FPS iteration: distance update + min (exact, no-FMA),
// block argmax with first-occurrence tie-break (strict-> locally, min-index
// on equal in the shuffle tree), 2 __syncthreads, winner coords re-read via
// broadcast global load (L1/L2-cached, all lanes same address).
__global__ __launch_bounds__(NT)
void fps_kernel(const float* __restrict__ pts, float* __restrict__ out_pts,
                int* __restrict__ idx_out, int M) {
  const int b = blockIdx.x;
  const int t = threadIdx.x;
  const int wave = t >> 6;
  const int lane = t & 63;
  const float* base = pts + (size_t)b * 3 * NN;   // [3][N] for this batch

  float px[PPT], py[PPT], pz[PPT], dist[PPT];
#pragma unroll
  for (int k = 0; k < PPT; ++k) {
    int n = t + k * NT;                           // coalesced: lane i -> addr i
    px[k] = base[n];
    py[k] = base[NN + n];
    pz[k] = base[2 * NN + n];
    dist[k] = 1e10f;                              // matches jnp.full(1e10)
  }

  __shared__ float s_val[NWAVES];
  __shared__ int   s_idx[NWAVES];
  __shared__ float s_red[NWAVES][3];
  __shared__ float s_ctr[3];
  __shared__ int   s_curi;

  // ---- centroid (once) ----
  float sx = 0.f, sy = 0.f, sz = 0.f;
#pragma unroll
  for (int k = 0; k < PPT; ++k) { sx += px[k]; sy += py[k]; sz += pz[k]; }
#pragma unroll
  for (int off = 32; off > 0; off >>= 1) {
    sx += __shfl_xor(sx, off);
    sy += __shfl_xor(sy, off);
    sz += __shfl_xor(sz, off);
  }
  if (lane == 0) { s_red[wave][0] = sx; s_red[wave][1] = sy; s_red[wave][2] = sz; }
  __syncthreads();
  if (t == 0) {
    float gx = 0.f, gy = 0.f, gz = 0.f;
    for (int w = 0; w < NWAVES; ++w) { gx += s_red[w][0]; gy += s_red[w][1]; gz += s_red[w][2]; }
    s_ctr[0] = gx / NN; s_ctr[1] = gy / NN; s_ctr[2] = gz / NN;  // /8192 exact
  }
  __syncthreads();
  const float ctx = s_ctr[0], cty = s_ctr[1], ctz = s_ctr[2];

  int ci; float cx, cy, cz;

  // Block argmax + broadcast of winner index and coordinates.
  auto argmax_bcast = [&](float v, int i) {
#pragma unroll
    for (int off = 32; off > 0; off >>= 1) {
      float ov = __shfl_xor(v, off);
      int   oi = __shfl_xor(i, off);
      if (ov > v || (ov == v && oi < i)) { v = ov; i = oi; }
    }
    if (lane == 0) { s_val[wave] = v; s_idx[wave] = i; }
    __syncthreads();                               // B1
    if (wave == 0) {
      float vv = (lane < NWAVES) ? s_val[lane] : -FLT_MAX;
      int   ii = (lane < NWAVES) ? s_idx[lane] : 0x7fffffff;
#pragma unroll
      for (int off = NWAVES / 2; off > 0; off >>= 1) {
        float ov = __shfl_xor(vv, off);
        int   oi = __shfl_xor(ii, off);
        if (ov > vv || (ov == vv && oi < ii)) { vv = ov; ii = oi; }
      }
      if (lane == 0) s_curi = ii;
    }
    __syncthreads();                               // B2
    ci = s_curi;
    // uniform-address broadcast loads (cached); avoids a 3rd barrier
    cx = base[ci]; cy = base[NN + ci]; cz = base[2 * NN + ci];
  };

  // ---- initial farthest = argmax of dist-to-centroid ----
  {
    float bv = -FLT_MAX; int bi = 0x7fffffff;
#pragma unroll
    for (int k = 0; k < PPT; ++k) {
      float dx = px[k] - ctx, dy = py[k] - cty, dz = pz[k] - ctz;
      float d = __fadd_rn(__fadd_rn(__fmul_rn(dx, dx), __fmul_rn(dy, dy)),
                          __fmul_rn(dz, dz));
      if (d > bv) { bv = d; bi = t + k * NT; }     // ascending n: first-occurrence
    }
    argmax_bcast(bv, bi);
  }

  // ---- FPS main loop: record, then update (M-1 updates total) ----
  for (int m = 0; m < M; ++m) {
    if (t == 0) {
      idx_out[b * M + m] = ci;
      size_t o = ((size_t)b * M + m) * 3;
      out_pts[o] = cx; out_pts[o + 1] = cy; out_pts[o + 2] = cz;
    }
    if (m == M - 1) break;

    float v = -FLT_MAX; int bk = 0;
#pragma unroll
    for (int k = 0; k < PPT; ++k) {
      // Exact (no-FMA) distance to match numpy: ((dx*dx + dy*dy) + dz*dz)
      float dx = px[k] - cx, dy = py[k] - cy, dz = pz[k] - cz;
      float d = __fadd_rn(__fadd_rn(__fmul_rn(dx, dx), __fmul_rn(dy, dy)),
                          __fmul_rn(dz, dz));
      float nd = fminf(dist[k], d);
      dist[k] = nd;
      if (nd > v) { v = nd; bk = k; }              // strict >: keeps lowest k
    }
    argmax_bcast(v, t + bk * NT);
  }
}

// Gather features: out[b,m,c] = feats[b,c,idx[b,m]].
// Block = 256 threads (one per c): writes coalesced (1 KB per block),
// reads strided-by-N gather absorbed by L2/L3 (whole features = 134 MB < L3).
__global__ __launch_bounds__(CC)
void gather_kernel(const float* __restrict__ feats, const int* __restrict__ idx,
                   float* __restrict__ out_f, int M) {
  const int bm = blockIdx.x;        // 0 .. B*M-1
  const int b = bm / M;
  const int m = bm - b * M;
  const int n = idx[bm];
  const int c = threadIdx.x;
  out_f[(size_t)bm * CC + c] = feats[((size_t)b * CC + c) * NN + n];
  (void)m;
}

extern "C" void kernel_launch(void* const* d_in, const int* in_sizes, int n_in,
                              void* d_out, int out_size, void* d_ws, size_t ws_size,
                              hipStream_t stream) {
  const float* points = (const float*)d_in[0];   // [B,3,N] f32
  const float* feats  = (const float*)d_in[1];   // [B,C,N] f32
  // num_points (d_in[2]) lives on device; derive M from out_size instead:
  // out_size = B*M*3 + B*M*C = M * B * (3+C)
  int M = out_size / (BB * (3 + CC));            // = 2048
  if (M <= 0) M = 1;

  float* out_pts = (float*)d_out;                        // [B,M,3]
  float* out_f   = (float*)d_out + (size_t)BB * M * 3;   // [B,M,C]
  int*   idx_ws  = (int*)d_ws;                           // B*M ints (128 KB)

  fps_kernel<<<dim3(BB), dim3(NT), 0, stream>>>(points, out_pts, idx_ws, M);
  gather_kernel<<<dim3(BB * M), dim3(CC), 0, stream>>>(feats, idx_ws, out_f, M);
}

// Round 2
// 2432.381 us; speedup vs baseline: 1.4201x; 1.4201x over previous
//
#include <hip/hip_runtime.h>
#include <cfloat>

// Problem constants (from reference): B=16, N=8192, C=256; M derived from out_size.
#define BB 16
#define NN 8192
#define CC 256
#define NT 512                 // threads per FPS block (8 waves)
#define PPT (NN / NT)          // 16 points per thread, held in registers
#define NWAVES (NT / 64)       // 8

// ---- u64 argmax key helpers -------------------------------------------------
// key = (float_bits(dist) << 32) | (u32)~index.
// dist >= 0 always, so float bits are monotone as unsigned. Max over keys =
// max dist; on equal dist, larger ~index = smaller index = numpy argmax
// first-occurrence tie-break.
__device__ __forceinline__ unsigned long long max64(unsigned long long a,
                                                    unsigned long long b) {
  return a > b ? a : b;
}

// One DPP reduce step on a u64 key (applied to both 32-bit halves).
// CTRL: 0xB1 = quad_perm[1,0,3,2] (xor1), 0x4E = quad_perm[2,3,0,1] (xor2),
//       0x124 = row_ror:4, 0x128 = row_ror:8. All VALU-pipe, ~10 cyc/step.
template <int CTRL>
__device__ __forceinline__ unsigned long long dpp_max64(unsigned long long x) {
  int lo = (int)(unsigned)x;
  int hi = (int)(unsigned)(x >> 32);
  int plo = __builtin_amdgcn_update_dpp(0, lo, CTRL, 0xF, 0xF, true);
  int phi = __builtin_amdgcn_update_dpp(0, hi, CTRL, 0xF, 0xF, true);
  unsigned long long p =
      ((unsigned long long)(unsigned)phi << 32) | (unsigned)plo;
  return max64(x, p);
}

// Full wave64 argmax: 4 cheap DPP steps (within 16-lane rows) + 2 LDS-pipe
// shuffles for the cross-row steps. All lanes end with the wave max.
__device__ __forceinline__ unsigned long long wave_argmax(unsigned long long k) {
  k = dpp_max64<0xB1>(k);    // xor 1
  k = dpp_max64<0x4E>(k);    // xor 2
  k = dpp_max64<0x124>(k);   // row_ror:4 -> covers xor4 equivalent
  k = dpp_max64<0x128>(k);   // row_ror:8 -> full 16-lane row
  k = max64(k, __shfl_xor(k, 16));
  k = max64(k, __shfl_xor(k, 32));
  return k;
}

// One workgroup per batch. Points in registers AND mirrored in LDS (96 KB)
// so the winner-coordinate broadcast is an LDS read, not a global load.
// Per iteration: exact (no-FMA) distance update + f32 local argmax, u64 key
// wave reduce (DPP), ONE barrier, redundant 8-key final reduce in every
// thread (double-buffered s_key kills the second barrier).
__global__ __launch_bounds__(NT)
void fps_kernel(const float* __restrict__ pts, float* __restrict__ out_pts,
                int* __restrict__ idx_out, int M) {
  const int b = blockIdx.x;
  const int t = threadIdx.x;
  const int wave = t >> 6;
  const int lane = t & 63;
  const float* base = pts + (size_t)b * 3 * NN;   // [3][N] for this batch

  __shared__ float s_px[NN], s_py[NN], s_pz[NN];  // 96 KB point mirror
  __shared__ unsigned long long s_key[2][NWAVES]; // double-buffered wave keys
  __shared__ float s_red[NWAVES][3];
  __shared__ float s_ctr[3];

  float px[PPT], py[PPT], pz[PPT], dist[PPT];
#pragma unroll
  for (int k = 0; k < PPT; ++k) {
    int n = t + k * NT;                           // coalesced
    px[k] = base[n];
    py[k] = base[NN + n];
    pz[k] = base[2 * NN + n];
    s_px[n] = px[k]; s_py[n] = py[k]; s_pz[n] = pz[k];
    dist[k] = 1e10f;                              // matches jnp.full(1e10)
  }

  // ---- centroid (once; startup latency irrelevant) ----
  float sx = 0.f, sy = 0.f, sz = 0.f;
#pragma unroll
  for (int k = 0; k < PPT; ++k) { sx += px[k]; sy += py[k]; sz += pz[k]; }
#pragma unroll
  for (int off = 32; off > 0; off >>= 1) {
    sx += __shfl_xor(sx, off);
    sy += __shfl_xor(sy, off);
    sz += __shfl_xor(sz, off);
  }
  if (lane == 0) { s_red[wave][0] = sx; s_red[wave][1] = sy; s_red[wave][2] = sz; }
  __syncthreads();    // also covers s_p* writes
  if (t == 0) {
    float gx = 0.f, gy = 0.f, gz = 0.f;
    for (int w = 0; w < NWAVES; ++w) { gx += s_red[w][0]; gy += s_red[w][1]; gz += s_red[w][2]; }
    s_ctr[0] = gx / NN; s_ctr[1] = gy / NN; s_ctr[2] = gz / NN;   // /8192 exact
  }
  __syncthreads();
  const float ctx = s_ctr[0], cty = s_ctr[1], ctz = s_ctr[2];

  int ep = 0;  // s_key epoch (parity double-buffer)

  // ---- initial farthest = argmax of dist-to-centroid ----
  int ci;
  {
    float bv = -FLT_MAX; int bi = 0;
#pragma unroll
    for (int k = 0; k < PPT; ++k) {
      float dx = px[k] - ctx, dy = py[k] - cty, dz = pz[k] - ctz;
      float d = __fadd_rn(__fadd_rn(__fmul_rn(dx, dx), __fmul_rn(dy, dy)),
                          __fmul_rn(dz, dz));
      if (d > bv) { bv = d; bi = t + k * NT; }   // ascending n: first-occurrence
    }
    unsigned long long key =
        ((unsigned long long)__float_as_uint(bv) << 32) | (unsigned)(~bi);
    key = wave_argmax(key);
    if (lane == 0) s_key[ep][wave] = key;
    __syncthreads();
    unsigned long long best = s_key[ep][0];
#pragma unroll
    for (int w = 1; w < NWAVES; ++w) best = max64(best, s_key[ep][w]);
    ci = (int)~(unsigned)best;
  }

  // ---- FPS main loop ----
  for (int m = 0; m < M; ++m) {
    // winner coords: uniform-address LDS broadcast (~120 cyc, vs ~200 global)
    float cx = s_px[ci], cy = s_py[ci], cz = s_pz[ci];
    if (t == 0) {
      idx_out[b * M + m] = ci;
      size_t o = ((size_t)b * M + m) * 3;
      out_pts[o] = cx; out_pts[o + 1] = cy; out_pts[o + 2] = cz;
    }
    if (m == M - 1) break;

    float v = -FLT_MAX; int bk = 0;
#pragma unroll
    for (int k = 0; k < PPT; ++k) {
      // Exact (no-FMA) distance to match numpy: ((dx*dx + dy*dy) + dz*dz)
      float dx = px[k] - cx, dy = py[k] - cy, dz = pz[k] - cz;
      float d = __fadd_rn(__fadd_rn(__fmul_rn(dx, dx), __fmul_rn(dy, dy)),
                          __fmul_rn(dz, dz));
      float nd = fminf(dist[k], d);
      dist[k] = nd;
      if (nd > v) { v = nd; bk = k; }            // strict >: keeps lowest k
    }
    unsigned long long key =
        ((unsigned long long)__float_as_uint(v) << 32) |
        (unsigned)(~(t + bk * NT));
    key = wave_argmax(key);

    ep ^= 1;                                     // double-buffer: no 2nd barrier
    if (lane == 0) s_key[ep][wave] = key;
    __syncthreads();
    unsigned long long best = s_key[ep][0];
#pragma unroll
    for (int w = 1; w < NWAVES; ++w) best = max64(best, s_key[ep][w]);
    ci = (int)~(unsigned)best;
  }
}

// Gather features: out[b,m,c] = feats[b,c,idx[b,m]].
// Block = 256 threads (one per c): writes coalesced (1 KB per block),
// reads strided-by-N gather absorbed by L2/L3 (whole features = 134 MB < L3).
__global__ __launch_bounds__(CC)
void gather_kernel(const float* __restrict__ feats, const int* __restrict__ idx,
                   float* __restrict__ out_f, int M) {
  const int bm = blockIdx.x;        // 0 .. B*M-1
  const int b = bm / M;
  const int n = idx[bm];
  const int c = threadIdx.x;
  out_f[(size_t)bm * CC + c] = feats[((size_t)b * CC + c) * NN + n];
}

extern "C" void kernel_launch(void* const* d_in, const int* in_sizes, int n_in,
                              void* d_out, int out_size, void* d_ws, size_t ws_size,
                              hipStream_t stream) {
  const float* points = (const float*)d_in[0];   // [B,3,N] f32
  const float* feats  = (const float*)d_in[1];   // [B,C,N] f32
  // num_points (d_in[2]) lives on device; derive M from out_size:
  // out_size = B*M*3 + B*M*C = M * B * (3+C)
  int M = out_size / (BB * (3 + CC));            // = 2048
  if (M <= 0) M = 1;

  float* out_pts = (float*)d_out;                        // [B,M,3]
  float* out_f   = (float*)d_out + (size_t)BB * M * 3;   // [B,M,C]
  int*   idx_ws  = (int*)d_ws;                           // B*M ints (128 KB)

  fps_kernel<<<dim3(BB), dim3(NT), 0, stream>>>(points, out_pts, idx_ws, M);
  gather_kernel<<<dim3(BB * M), dim3(CC), 0, stream>>>(feats, idx_ws, out_f, M);
}

// Round 3
// 2243.697 us; speedup vs baseline: 1.5395x; 1.0841x over previous
//
#include <hip/hip_runtime.h>
#include <cfloat>

// Problem constants: B=16, N=8192, C=256; M derived from out_size (=2048).
#define BB 16
#define NN 8192
#define CC 256
#define NT 512                  // threads per FPS block (8 waves)
#define PPT 16                  // points per thread
#define NPAIR (PPT / 2)         // 8 packed f32x2 pairs
#define NWAVES (NT / 64)        // 8
#define TBLOCKS 240             // transpose helper blocks (fill idle CUs)
#define NTILES (BB * (CC / 64) * (NN / 64))   // 16*4*128 = 8192 64x64 tiles

typedef float v2f __attribute__((ext_vector_type(2)));

// Shared memory: FPS view (128 KB point mirror + reduce slots) unioned with
// the transpose tile view. 128.3 KB static LDS -> 1 block/CU for every block,
// so transpose blocks never co-reside with (and never slow down) FPS blocks.
struct SmemFPS {
  float4 p4[NN];                          // 128 KB point mirror (x,y,z,0)
  unsigned long long key[2][NWAVES];      // double-buffered wave keys
  float red[NWAVES][3];
  float ctr[3];
};
struct SmemT {
  float tile[64][65];                     // padded: conflict-free transpose
};
union Smem { SmemFPS f; SmemT t; };

// key = (float_bits(dist) << 32) | (u32)~index. dist >= 0 -> bits monotone.
// max key = max dist; tie -> larger ~idx = smaller idx = numpy first-occurrence.
__device__ __forceinline__ unsigned long long max64(unsigned long long a,
                                                    unsigned long long b) {
  return a > b ? a : b;
}

// One DPP max step on a u64 key (both 32-bit halves move with same pattern).
// bound_ctrl=1: lanes with no valid source read 0; key==0 never wins (its
// index field would be 0xffffffff) so max(x,0)=x is harmless.
template <int CTRL>
__device__ __forceinline__ unsigned long long dpp_max64(unsigned long long x) {
  int lo = (int)(unsigned)x;
  int hi = (int)(unsigned)(x >> 32);
  int plo = __builtin_amdgcn_update_dpp(0, lo, CTRL, 0xF, 0xF, true);
  int phi = __builtin_amdgcn_update_dpp(0, hi, CTRL, 0xF, 0xF, true);
  unsigned long long p =
      ((unsigned long long)(unsigned)phi << 32) | (unsigned)plo;
  return max64(x, p);
}

// Wave64 max entirely on the VALU pipe (no ds_swizzle): 4 row steps give every
// lane its 16-row max; row_bcast15 (0x142) then row_bcast31 (0x143) funnel the
// cross-row max into lane 63 (standard GCN reduction idiom). Lane 63 writes.
__device__ __forceinline__ unsigned long long wave_max63(unsigned long long k) {
  k = dpp_max64<0xB1>(k);    // quad_perm xor1
  k = dpp_max64<0x4E>(k);    // quad_perm xor2
  k = dpp_max64<0x124>(k);   // row_ror:4
  k = dpp_max64<0x128>(k);   // row_ror:8 -> full 16-lane row max, all lanes
  k = dpp_max64<0x142>(k);   // row_bcast15: rows 1,3 combine rows 0,2
  k = dpp_max64<0x143>(k);   // row_bcast31: lanes 32-63 combine low half
  return k;                  // valid in lane 63
}

// blockIdx < BB: one FPS workgroup per batch.
// blockIdx >= BB (only when do_trans): grid-stride transpose of features
// [B][C][N] -> trans [B][N][C], hidden under the 2 ms FPS on idle CUs.
__global__ __launch_bounds__(NT)
void fps_fused_kernel(const float* __restrict__ pts,
                      const float* __restrict__ feats,
                      float* __restrict__ out_pts,
                      int* __restrict__ idx_out,
                      float* __restrict__ trans, int M, int do_trans) {
  __shared__ Smem sm;
  const int t = threadIdx.x;

  if (blockIdx.x >= BB) {
    // ---------------- transpose path ----------------
    if (!do_trans) return;
    for (int tileId = blockIdx.x - BB; tileId < NTILES; tileId += TBLOCKS) {
      int b  = tileId / ((CC / 64) * (NN / 64));
      int r  = tileId % ((CC / 64) * (NN / 64));
      int ct = r / (NN / 64);           // c-tile 0..3
      int nt = r % (NN / 64);           // n-tile 0..127
      const float* src = feats + ((size_t)b * CC + ct * 64) * NN + nt * 64;
      float* dst = trans + ((size_t)b * NN + nt * 64) * CC + ct * 64;
#pragma unroll
      for (int i = 0; i < 2; ++i) {     // 1024 float4 loads / 512 threads
        int f = t + i * NT;
        int c = f >> 4, n4 = f & 15;    // 16 float4 per c-row
        float4 v = *(const float4*)(src + (size_t)c * NN + n4 * 4);
        sm.t.tile[c][n4 * 4 + 0] = v.x;
        sm.t.tile[c][n4 * 4 + 1] = v.y;
        sm.t.tile[c][n4 * 4 + 2] = v.z;
        sm.t.tile[c][n4 * 4 + 3] = v.w;
      }
      __syncthreads();
#pragma unroll
      for (int i = 0; i < 2; ++i) {
        int f = t + i * NT;
        int n = f >> 4, c4 = f & 15;    // 16 float4 per n-row
        float4 o;
        o.x = sm.t.tile[c4 * 4 + 0][n];
        o.y = sm.t.tile[c4 * 4 + 1][n];
        o.z = sm.t.tile[c4 * 4 + 2][n];
        o.w = sm.t.tile[c4 * 4 + 3][n];
        *(float4*)(dst + (size_t)n * CC + c4 * 4) = o;
      }
      __syncthreads();                  // tile reuse across grid-stride iters
    }
    return;
  }

  // ---------------- FPS path ----------------
  const int b = blockIdx.x;
  const int wave = t >> 6;
  const int lane = t & 63;
  const float* base = pts + (size_t)b * 3 * NN;   // [3][N] for this batch

  v2f px2[NPAIR], py2[NPAIR], pz2[NPAIR], dist2[NPAIR];
#pragma unroll
  for (int j = 0; j < NPAIR; ++j) {
    int n0 = t + (2 * j) * NT;                    // coalesced loads
    int n1 = t + (2 * j + 1) * NT;
    float x0 = base[n0], y0 = base[NN + n0], z0 = base[2 * NN + n0];
    float x1 = base[n1], y1 = base[NN + n1], z1 = base[2 * NN + n1];
    px2[j] = (v2f){x0, x1};
    py2[j] = (v2f){y0, y1};
    pz2[j] = (v2f){z0, z1};
    sm.f.p4[n0] = make_float4(x0, y0, z0, 0.f);
    sm.f.p4[n1] = make_float4(x1, y1, z1, 0.f);
    dist2[j] = (v2f){1e10f, 1e10f};               // matches jnp.full(1e10)
  }

  // ---- centroid (one-time; latency irrelevant) ----
  float sx = 0.f, sy = 0.f, sz = 0.f;
#pragma unroll
  for (int j = 0; j < NPAIR; ++j) {
    sx += px2[j].x; sx += px2[j].y;
    sy += py2[j].x; sy += py2[j].y;
    sz += pz2[j].x; sz += pz2[j].y;
  }
#pragma unroll
  for (int off = 32; off > 0; off >>= 1) {
    sx += __shfl_xor(sx, off);
    sy += __shfl_xor(sy, off);
    sz += __shfl_xor(sz, off);
  }
  if (lane == 0) { sm.f.red[wave][0] = sx; sm.f.red[wave][1] = sy; sm.f.red[wave][2] = sz; }
  __syncthreads();    // also covers p4 staging writes
  if (t == 0) {
    float gx = 0.f, gy = 0.f, gz = 0.f;
    for (int w = 0; w < NWAVES; ++w) { gx += sm.f.red[w][0]; gy += sm.f.red[w][1]; gz += sm.f.red[w][2]; }
    sm.f.ctr[0] = gx / NN; sm.f.ctr[1] = gy / NN; sm.f.ctr[2] = gz / NN;  // /8192 exact
  }
  __syncthreads();
  const float ctx = sm.f.ctr[0], cty = sm.f.ctr[1], ctz = sm.f.ctr[2];

  int ep = 0;   // s_key epoch (parity double-buffer -> one barrier per iter)
  int ci;

  // Shared tail: wave reduce via DPP, single barrier, redundant 8-key tree.
  auto reduce_tail = [&](float v, int bk) {
    unsigned long long key =
        ((unsigned long long)__float_as_uint(v) << 32) |
        (unsigned)(~(t + bk * NT));
    key = wave_max63(key);
    ep ^= 1;
    if (lane == 63) sm.f.key[ep][wave] = key;
    __syncthreads();
    unsigned long long k0 = max64(sm.f.key[ep][0], sm.f.key[ep][1]);
    unsigned long long k1 = max64(sm.f.key[ep][2], sm.f.key[ep][3]);
    unsigned long long k2 = max64(sm.f.key[ep][4], sm.f.key[ep][5]);
    unsigned long long k3 = max64(sm.f.key[ep][6], sm.f.key[ep][7]);
    ci = (int)~(unsigned)max64(max64(k0, k1), max64(k2, k3));
  };

  // ---- initial farthest = argmax of dist-to-centroid (no dist update) ----
  {
    v2f c2x = {ctx, ctx}, c2y = {cty, cty}, c2z = {ctz, ctz};
    v2f nd2[NPAIR];
    float v = -FLT_MAX;
    {
#pragma clang fp contract(off)
#pragma unroll
      for (int j = 0; j < NPAIR; ++j) {
        v2f dx = px2[j] - c2x, dy = py2[j] - c2y, dz = pz2[j] - c2z;
        v2f d = (dx * dx + dy * dy) + dz * dz;   // exact: pk_mul/pk_add, no fma
        nd2[j] = d;
        v = fmaxf(fmaxf(v, d.x), d.y);           // v_max3_f32
      }
    }
    int bk = 0;
#pragma unroll
    for (int k = PPT - 1; k >= 0; --k) {         // descending: keeps smallest k
      float ndk = (k & 1) ? nd2[k >> 1].y : nd2[k >> 1].x;
      if (ndk == v) bk = k;                      // first-occurrence tie-break
    }
    reduce_tail(v, bk);
  }

  // ---- FPS main loop ----
  for (int m = 0; m < M; ++m) {
    float4 c4 = sm.f.p4[ci];                     // one uniform ds_read_b128
    if (t == 0) {
      idx_out[b * M + m] = ci;
      size_t o = ((size_t)b * M + m) * 3;
      out_pts[o] = c4.x; out_pts[o + 1] = c4.y; out_pts[o + 2] = c4.z;
    }
    if (m == M - 1) break;

    v2f c2x = {c4.x, c4.x}, c2y = {c4.y, c4.y}, c2z = {c4.z, c4.z};
    v2f nd2[NPAIR];
    float v = -FLT_MAX;
    {
#pragma clang fp contract(off)
#pragma unroll
      for (int j = 0; j < NPAIR; ++j) {
        v2f dx = px2[j] - c2x, dy = py2[j] - c2y, dz = pz2[j] - c2z;
        v2f d = (dx * dx + dy * dy) + dz * dz;   // ((dx2+dy2)+dz2), exact
        v2f nd;
        nd.x = fminf(dist2[j].x, d.x);
        nd.y = fminf(dist2[j].y, d.y);
        dist2[j] = nd;
        nd2[j] = nd;
        v = fmaxf(fmaxf(v, nd.x), nd.y);         // v_max3_f32 chain
      }
    }
    int bk = 0;
#pragma unroll
    for (int k = PPT - 1; k >= 0; --k) {
      float ndk = (k & 1) ? nd2[k >> 1].y : nd2[k >> 1].x;
      if (ndk == v) bk = k;
    }
    reduce_tail(v, bk);
  }
}

// Gather from transposed features: fully coalesced float4 both sides.
// One wave per (b,m): 64 lanes x float4 = 1 KB row copy.
__global__ __launch_bounds__(256)
void gather_t_kernel(const float* __restrict__ trans,
                     const int* __restrict__ idx,
                     float* __restrict__ out_f, int M) {
  int gm = blockIdx.x * 4 + (threadIdx.x >> 6);
  if (gm >= BB * M) return;
  int lane = threadIdx.x & 63;
  int b = gm / M;
  int n = idx[gm];
  float4 v = *(const float4*)(trans + ((size_t)b * NN + n) * CC + lane * 4);
  *(float4*)(out_f + (size_t)gm * CC + lane * 4) = v;
}

// Fallback gather (ws too small for transpose): scattered reads, L2/L3-bound.
__global__ __launch_bounds__(CC)
void gather_kernel(const float* __restrict__ feats, const int* __restrict__ idx,
                   float* __restrict__ out_f, int M) {
  const int bm = blockIdx.x;
  const int b = bm / M;
  const int n = idx[bm];
  const int c = threadIdx.x;
  out_f[(size_t)bm * CC + c] = feats[((size_t)b * CC + c) * NN + n];
}

extern "C" void kernel_launch(void* const* d_in, const int* in_sizes, int n_in,
                              void* d_out, int out_size, void* d_ws, size_t ws_size,
                              hipStream_t stream) {
  const float* points = (const float*)d_in[0];   // [B,3,N] f32
  const float* feats  = (const float*)d_in[1];   // [B,C,N] f32
  // out_size = B*M*3 + B*M*C = M * B * (3+C)
  int M = out_size / (BB * (3 + CC));            // = 2048
  if (M <= 0) M = 1;

  float* out_pts = (float*)d_out;                        // [B,M,3]
  float* out_f   = (float*)d_out + (size_t)BB * M * 3;   // [B,M,C]

  int* idx_ws = (int*)d_ws;                              // B*M ints
  size_t idx_bytes = (((size_t)BB * M * sizeof(int)) + 255) & ~(size_t)255;
  size_t trans_bytes = (size_t)BB * NN * CC * sizeof(float);   // 134.2 MB
  bool use_t = (ws_size >= idx_bytes + trans_bytes);
  float* trans = (float*)((char*)d_ws + idx_bytes);

  int grid = use_t ? (BB + TBLOCKS) : BB;
  fps_fused_kernel<<<dim3(grid), dim3(NT), 0, stream>>>(
      points, feats, out_pts, idx_ws, trans, M, use_t ? 1 : 0);

  if (use_t) {
    gather_t_kernel<<<dim3((BB * M + 3) / 4), dim3(256), 0, stream>>>(
        trans, idx_ws, out_f, M);
  } else {
    gather_kernel<<<dim3(BB * M), dim3(CC), 0, stream>>>(feats, idx_ws, out_f, M);
  }
}

// Round 4
// 1945.140 us; speedup vs baseline: 1.7758x; 1.1535x over previous
//
#include <hip/hip_runtime.h>
#include <cfloat>

// Problem constants: B=16, N=8192, C=256; M derived from out_size (=2048).
#define BB 16
#define NN 8192
#define CC 256
#define NT 512                  // threads per FPS block (8 waves)
#define PPT 16                  // points per thread
#define NPAIR (PPT / 2)         // 8 packed f32x2 pairs
#define NWAVES (NT / 64)        // 8
#define TBLOCKS 240             // transpose helper blocks (fill idle CUs)
#define NTILES (BB * (CC / 64) * (NN / 64))   // 16*4*128 = 8192 64x64 tiles

typedef float    v2f __attribute__((ext_vector_type(2)));
typedef unsigned v2u __attribute__((ext_vector_type(2)));
typedef unsigned uu;
typedef unsigned long long ull;

// Shared memory. FPS view: separate x/y/z coord arrays -> winner-coord fetch
// is 3x b32 same-address broadcast (measured conflict-free in R2; the R3
// b128 uniform reads measured 1024 conflict-cycles/iter). Union with the
// transpose tile so both paths fit one 98.5 KB block (1 block/CU each).
struct SmemFPS {
  float px[NN], py[NN], pz[NN];           // 96 KB point mirror
  ull   key[2][NWAVES];                   // double-buffered wave keys
  float red[NWAVES][3];
  float ctr[3];
};
struct SmemT {
  float tile[64][65];                     // padded: conflict-free transpose
};
union Smem { SmemFPS f; SmemT t; };

// ---- guaranteed-packed f32 math (VOP3P). Each half is a plain IEEE f32 op
// (round-to-nearest-even), bit-identical to the scalar version. ----
__device__ __forceinline__ v2f pk_sub(v2f a, v2f b) {
  v2f d;
  asm("v_pk_add_f32 %0, %1, %2 neg_lo:[0,1] neg_hi:[0,1]"
      : "=v"(d) : "v"(a), "v"(b));
  return d;
}
__device__ __forceinline__ v2f pk_mul(v2f a, v2f b) {
  v2f d;
  asm("v_pk_mul_f32 %0, %1, %2" : "=v"(d) : "v"(a), "v"(b));
  return d;
}
__device__ __forceinline__ v2f pk_add(v2f a, v2f b) {
  v2f d;
  asm("v_pk_add_f32 %0, %1, %2" : "=v"(d) : "v"(a), "v"(b));
  return d;
}

__device__ __forceinline__ uu umin2(uu a, uu b) { return a < b ? a : b; }
__device__ __forceinline__ uu umax2(uu a, uu b) { return a > b ? a : b; }

// key = (dist_bits << 32) | ~index. dist >= 0 -> u32 bit order == f32 order.
// max key = max dist; tie -> larger ~idx = smaller idx = numpy first-occurrence.
__device__ __forceinline__ ull max64(ull a, ull b) { return a > b ? a : b; }

// One DPP max step on a u64 key (both 32-bit halves move with same pattern).
template <int CTRL>
__device__ __forceinline__ ull dpp_max64(ull x) {
  int lo = (int)(uu)x;
  int hi = (int)(uu)(x >> 32);
  int plo = __builtin_amdgcn_update_dpp(0, lo, CTRL, 0xF, 0xF, true);
  int phi = __builtin_amdgcn_update_dpp(0, hi, CTRL, 0xF, 0xF, true);
  ull p = ((ull)(uu)phi << 32) | (uu)plo;
  return max64(x, p);
}

// Wave64 max funneled into lane 63, all on the VALU pipe (no LDS-pipe ops).
__device__ __forceinline__ ull wave_max63(ull k) {
  k = dpp_max64<0xB1>(k);    // quad_perm xor1
  k = dpp_max64<0x4E>(k);    // quad_perm xor2
  k = dpp_max64<0x124>(k);   // row_ror:4
  k = dpp_max64<0x128>(k);   // row_ror:8 -> full 16-lane row max
  k = dpp_max64<0x142>(k);   // row_bcast15
  k = dpp_max64<0x143>(k);   // row_bcast31 -> lane 63 has wave max
  return k;
}

// blockIdx < BB: one FPS workgroup per batch.
// blockIdx >= BB (when do_trans): grid-stride transpose of features
// [B][C][N] -> trans [B][N][C], hidden under FPS on the idle 240 CUs.
__global__ __launch_bounds__(NT)
void fps_fused_kernel(const float* __restrict__ pts,
                      const float* __restrict__ feats,
                      float* __restrict__ out_pts,
                      int* __restrict__ idx_out,
                      float* __restrict__ trans, int M, int do_trans) {
  __shared__ Smem sm;
  const int t = threadIdx.x;

  if (blockIdx.x >= BB) {
    // ---------------- transpose path ----------------
    if (!do_trans) return;
    for (int tileId = blockIdx.x - BB; tileId < NTILES; tileId += TBLOCKS) {
      int b  = tileId / ((CC / 64) * (NN / 64));
      int r  = tileId % ((CC / 64) * (NN / 64));
      int ct = r / (NN / 64);           // c-tile 0..3
      int nt = r % (NN / 64);           // n-tile 0..127
      const float* src = feats + ((size_t)b * CC + ct * 64) * NN + nt * 64;
      float* dst = trans + ((size_t)b * NN + nt * 64) * CC + ct * 64;
#pragma unroll
      for (int i = 0; i < 2; ++i) {     // 1024 float4 loads / 512 threads
        int f = t + i * NT;
        int c = f >> 4, n4 = f & 15;
        float4 v = *(const float4*)(src + (size_t)c * NN + n4 * 4);
        sm.t.tile[c][n4 * 4 + 0] = v.x;
        sm.t.tile[c][n4 * 4 + 1] = v.y;
        sm.t.tile[c][n4 * 4 + 2] = v.z;
        sm.t.tile[c][n4 * 4 + 3] = v.w;
      }
      __syncthreads();
#pragma unroll
      for (int i = 0; i < 2; ++i) {
        int f = t + i * NT;
        int n = f >> 4, c4 = f & 15;
        float4 o;
        o.x = sm.t.tile[c4 * 4 + 0][n];
        o.y = sm.t.tile[c4 * 4 + 1][n];
        o.z = sm.t.tile[c4 * 4 + 2][n];
        o.w = sm.t.tile[c4 * 4 + 3][n];
        *(float4*)(dst + (size_t)n * CC + c4 * 4) = o;
      }
      __syncthreads();                  // tile reuse across grid-stride iters
    }
    return;
  }

  // ---------------- FPS path ----------------
  const int b = blockIdx.x;
  const int wave = t >> 6;
  const int lane = t & 63;
  const float* base = pts + (size_t)b * 3 * NN;   // [3][N] for this batch

  v2f px2[NPAIR], py2[NPAIR], pz2[NPAIR];
  v2u dist2[NPAIR];
  const uu INIT = __float_as_uint(1e10f);         // matches jnp.full(1e10)
#pragma unroll
  for (int j = 0; j < NPAIR; ++j) {
    int n0 = t + (2 * j) * NT;                    // coalesced loads
    int n1 = t + (2 * j + 1) * NT;
    float x0 = base[n0], y0 = base[NN + n0], z0 = base[2 * NN + n0];
    float x1 = base[n1], y1 = base[NN + n1], z1 = base[2 * NN + n1];
    px2[j] = (v2f){x0, x1};
    py2[j] = (v2f){y0, y1};
    pz2[j] = (v2f){z0, z1};
    sm.f.px[n0] = x0; sm.f.py[n0] = y0; sm.f.pz[n0] = z0;
    sm.f.px[n1] = x1; sm.f.py[n1] = y1; sm.f.pz[n1] = z1;
    dist2[j] = (v2u){INIT, INIT};
  }

  // ---- centroid (one-time; latency irrelevant) ----
  float sx = 0.f, sy = 0.f, sz = 0.f;
#pragma unroll
  for (int j = 0; j < NPAIR; ++j) {
    sx += px2[j].x; sx += px2[j].y;
    sy += py2[j].x; sy += py2[j].y;
    sz += pz2[j].x; sz += pz2[j].y;
  }
#pragma unroll
  for (int off = 32; off > 0; off >>= 1) {
    sx += __shfl_xor(sx, off);
    sy += __shfl_xor(sy, off);
    sz += __shfl_xor(sz, off);
  }
  if (lane == 0) { sm.f.red[wave][0] = sx; sm.f.red[wave][1] = sy; sm.f.red[wave][2] = sz; }
  __syncthreads();    // also covers coord-mirror staging writes
  if (t == 0) {
    float gx = 0.f, gy = 0.f, gz = 0.f;
    for (int w = 0; w < NWAVES; ++w) { gx += sm.f.red[w][0]; gy += sm.f.red[w][1]; gz += sm.f.red[w][2]; }
    sm.f.ctr[0] = gx / NN; sm.f.ctr[1] = gy / NN; sm.f.ctr[2] = gz / NN;  // /8192 exact
  }
  __syncthreads();
  const float ctx = sm.f.ctr[0], cty = sm.f.ctr[1], ctz = sm.f.ctr[2];

  int ep = 0;   // key epoch (parity double-buffer -> one barrier per iter)
  int ci;

  // Tail: u64 key wave reduce via DPP (VALU only), lane-63 write, ONE
  // barrier, then a SPREAD b64 read (lane reads key[lane&7]; 8 distinct
  // addresses -> conflict-free, can't be merged into b128) + 3 DPP steps so
  // every lane holds the block max.
  auto reduce_tail = [&](uu v, int bk) {
    ull key = ((ull)v << 32) | (uu)(~(t + (bk << 9)));   // bk*NT, NT=512
    key = wave_max63(key);
    ep ^= 1;
    if (lane == 63) sm.f.key[ep][wave] = key;
    __syncthreads();
    ull kk = sm.f.key[ep][lane & 7];   // spread ds_read_b64
    kk = dpp_max64<0xB1>(kk);          // xor1 within 8-key group
    kk = dpp_max64<0x4E>(kk);          // xor2
    kk = dpp_max64<0x124>(kk);         // row_ror:4 -> completes all-8 max
    ci = (int)~(uu)kk;
  };

  // ---- initial farthest = argmax of dist-to-centroid (no dist update) ----
  {
    v2f c2x = {ctx, ctx}, c2y = {cty, cty}, c2z = {ctz, ctz};
    v2u nd2[NPAIR];
    uu v = 0u;
#pragma unroll
    for (int j = 0; j < NPAIR; ++j) {
      v2f dx = pk_sub(px2[j], c2x);
      v2f dy = pk_sub(py2[j], c2y);
      v2f dz = pk_sub(pz2[j], c2z);
      // exact numpy order: ((dx*dx + dy*dy) + dz*dz), no FMA
      v2f d = pk_add(pk_add(pk_mul(dx, dx), pk_mul(dy, dy)), pk_mul(dz, dz));
      v2u du = (v2u){__float_as_uint(d.x), __float_as_uint(d.y)};
      nd2[j] = du;
      v = umax2(v, umax2(du.x, du.y));           // v_max3_u32
    }
    int bk = 0;
#pragma unroll
    for (int k = PPT - 1; k >= 0; --k) {         // descending: keeps smallest k
      uu ndk = (k & 1) ? nd2[k >> 1].y : nd2[k >> 1].x;
      if (ndk == v) bk = k;                      // first-occurrence tie-break
    }
    reduce_tail(v, bk);
  }

  // ---- FPS main loop ----
  for (int m = 0; m < M; ++m) {
    // winner coords: 3x b32 same-address broadcast (conflict-free)
    float cx = sm.f.px[ci], cy = sm.f.py[ci], cz = sm.f.pz[ci];
    if (t == 0) {
      idx_out[b * M + m] = ci;
      size_t o = ((size_t)b * M + m) * 3;
      out_pts[o] = cx; out_pts[o + 1] = cy; out_pts[o + 2] = cz;
    }
    if (m == M - 1) break;

    v2f c2x = {cx, cx}, c2y = {cy, cy}, c2z = {cz, cz};
    v2u nd2[NPAIR];
    uu v = 0u;
#pragma unroll
    for (int j = 0; j < NPAIR; ++j) {
      v2f dx = pk_sub(px2[j], c2x);
      v2f dy = pk_sub(py2[j], c2y);
      v2f dz = pk_sub(pz2[j], c2z);
      v2f d = pk_add(pk_add(pk_mul(dx, dx), pk_mul(dy, dy)), pk_mul(dz, dz));
      // dists >= 0 -> u32 min/max on the bits == f32 min/max, no canonicalize
      v2u nd;
      nd.x = umin2(dist2[j].x, __float_as_uint(d.x));
      nd.y = umin2(dist2[j].y, __float_as_uint(d.y));
      dist2[j] = nd;
      nd2[j] = nd;
      v = umax2(v, umax2(nd.x, nd.y));           // v_max3_u32 chain
    }
    int bk = 0;
#pragma unroll
    for (int k = PPT - 1; k >= 0; --k) {
      uu ndk = (k & 1) ? nd2[k >> 1].y : nd2[k >> 1].x;
      if (ndk == v) bk = k;
    }
    reduce_tail(v, bk);
  }
}

// Gather from transposed features: fully coalesced float4 both sides.
__global__ __launch_bounds__(256)
void gather_t_kernel(const float* __restrict__ trans,
                     const int* __restrict__ idx,
                     float* __restrict__ out_f, int M) {
  int gm = blockIdx.x * 4 + (threadIdx.x >> 6);
  if (gm >= BB * M) return;
  int lane = threadIdx.x & 63;
  int b = gm / M;
  int n = idx[gm];
  float4 v = *(const float4*)(trans + ((size_t)b * NN + n) * CC + lane * 4);
  *(float4*)(out_f + (size_t)gm * CC + lane * 4) = v;
}

// Fallback gather (ws too small for transpose): scattered reads, L2/L3-bound.
__global__ __launch_bounds__(CC)
void gather_kernel(const float* __restrict__ feats, const int* __restrict__ idx,
                   float* __restrict__ out_f, int M) {
  const int bm = blockIdx.x;
  const int b = bm / M;
  const int n = idx[bm];
  const int c = threadIdx.x;
  out_f[(size_t)bm * CC + c] = feats[((size_t)b * CC + c) * NN + n];
}

extern "C" void kernel_launch(void* const* d_in, const int* in_sizes, int n_in,
                              void* d_out, int out_size, void* d_ws, size_t ws_size,
                              hipStream_t stream) {
  const float* points = (const float*)d_in[0];   // [B,3,N] f32
  const float* feats  = (const float*)d_in[1];   // [B,C,N] f32
  // out_size = B*M*3 + B*M*C = M * B * (3+C)
  int M = out_size / (BB * (3 + CC));            // = 2048
  if (M <= 0) M = 1;

  float* out_pts = (float*)d_out;                        // [B,M,3]
  float* out_f   = (float*)d_out + (size_t)BB * M * 3;   // [B,M,C]

  int* idx_ws = (int*)d_ws;                              // B*M ints
  size_t idx_bytes = (((size_t)BB * M * sizeof(int)) + 255) & ~(size_t)255;
  size_t trans_bytes = (size_t)BB * NN * CC * sizeof(float);   // 134.2 MB
  bool use_t = (ws_size >= idx_bytes + trans_bytes);
  float* trans = (float*)((char*)d_ws + idx_bytes);

  int grid = use_t ? (BB + TBLOCKS) : BB;
  fps_fused_kernel<<<dim3(grid), dim3(NT), 0, stream>>>(
      points, feats, out_pts, idx_ws, trans, M, use_t ? 1 : 0);

  if (use_t) {
    gather_t_kernel<<<dim3((BB * M + 3) / 4), dim3(256), 0, stream>>>(
        trans, idx_ws, out_f, M);
  } else {
    gather_kernel<<<dim3(BB * M), dim3(CC), 0, stream>>>(feats, idx_ws, out_f, M);
  }
}

// Round 5
// 1909.347 us; speedup vs baseline: 1.8091x; 1.0187x over previous
//
#include <hip/hip_runtime.h>
#include <cfloat>

// Problem constants: B=16, N=8192, C=256; M derived from out_size (=2048).
#define BB 16
#define NN 8192
#define CC 256
#define NT 512                  // threads per FPS block (8 waves)
#define PPT 16                  // points per thread
#define NPAIR (PPT / 2)         // 8 packed f32x2 pairs
#define NWAVES (NT / 64)        // 8
#define TBLOCKS 240             // transpose helper blocks (fill idle CUs)
#define NTILES (BB * (CC / 64) * (NN / 64))   // 16*4*128 = 8192 64x64 tiles

typedef float    v2f __attribute__((ext_vector_type(2)));
typedef unsigned v2u __attribute__((ext_vector_type(2)));
typedef unsigned uu;
typedef unsigned long long ull;

// Barrier that waits ONLY on LDS (lgkmcnt), not vmcnt. __syncthreads emits
// "s_waitcnt vmcnt(0) lgkmcnt(0); s_barrier" — the vmcnt(0) forces wave 0 to
// wait ~300 cyc for its per-iteration global stores (idx/out_pts) to RETIRE
// before the barrier, stalling all 8 waves every iteration. Our only
// cross-wave data is the LDS key write -> lgkmcnt(0) suffices; global stores
// are drained at s_endpgm.
#define LDS_BARRIER() __asm__ __volatile__("s_waitcnt lgkmcnt(0)\n\ts_barrier" ::: "memory")

// Shared memory. FPS view: separate x/y/z coord arrays -> winner-coord fetch
// is 3x b32 same-address broadcast (conflict-free). Union with the transpose
// tile so both paths fit one 98.5 KB block (1 block/CU each).
// NOTE (R4 measured): SQ_LDS_BANK_CONFLICT == 2^21 comes from the transpose
// tile's 2-way aliasing (benign per m136), NOT from the FPS path.
struct SmemFPS {
  float px[NN], py[NN], pz[NN];           // 96 KB point mirror
  ull   key[2][NWAVES];                   // double-buffered wave keys
  float red[NWAVES][3];
  float ctr[3];
};
struct SmemT {
  float tile[64][65];                     // padded transpose tile
};
union Smem { SmemFPS f; SmemT t; };

// ---- guaranteed-packed f32 math (VOP3P). Each half is a plain IEEE f32 op
// (round-to-nearest-even), bit-identical to the scalar version. ----
__device__ __forceinline__ v2f pk_sub(v2f a, v2f b) {
  v2f d;
  asm("v_pk_add_f32 %0, %1, %2 neg_lo:[0,1] neg_hi:[0,1]"
      : "=v"(d) : "v"(a), "v"(b));
  return d;
}
__device__ __forceinline__ v2f pk_mul(v2f a, v2f b) {
  v2f d;
  asm("v_pk_mul_f32 %0, %1, %2" : "=v"(d) : "v"(a), "v"(b));
  return d;
}
__device__ __forceinline__ v2f pk_add(v2f a, v2f b) {
  v2f d;
  asm("v_pk_add_f32 %0, %1, %2" : "=v"(d) : "v"(a), "v"(b));
  return d;
}

__device__ __forceinline__ uu umin2(uu a, uu b) { return a < b ? a : b; }
__device__ __forceinline__ uu umax2(uu a, uu b) { return a > b ? a : b; }

// key = (dist_bits << 32) | ~index. dist >= 0 -> u32 bit order == f32 order.
// max key = max dist; tie -> larger ~idx = smaller idx = numpy first-occurrence.
__device__ __forceinline__ ull max64(ull a, ull b) { return a > b ? a : b; }

// One DPP max step on a u64 key (both 32-bit halves move with same pattern).
template <int CTRL>
__device__ __forceinline__ ull dpp_max64(ull x) {
  int lo = (int)(uu)x;
  int hi = (int)(uu)(x >> 32);
  int plo = __builtin_amdgcn_update_dpp(0, lo, CTRL, 0xF, 0xF, true);
  int phi = __builtin_amdgcn_update_dpp(0, hi, CTRL, 0xF, 0xF, true);
  ull p = ((ull)(uu)phi << 32) | (uu)plo;
  return max64(x, p);
}

// Wave64 max funneled into lane 63, all on the VALU pipe (no LDS-pipe ops).
__device__ __forceinline__ ull wave_max63(ull k) {
  k = dpp_max64<0xB1>(k);    // quad_perm xor1
  k = dpp_max64<0x4E>(k);    // quad_perm xor2
  k = dpp_max64<0x124>(k);   // row_ror:4
  k = dpp_max64<0x128>(k);   // row_ror:8 -> full 16-lane row max
  k = dpp_max64<0x142>(k);   // row_bcast15
  k = dpp_max64<0x143>(k);   // row_bcast31 -> lane 63 has wave max
  return k;
}

// blockIdx < BB: one FPS workgroup per batch.
// blockIdx >= BB (when do_trans): grid-stride transpose of features
// [B][C][N] -> trans [B][N][C], hidden under FPS on the idle 240 CUs.
__global__ __launch_bounds__(NT)
void fps_fused_kernel(const float* __restrict__ pts,
                      const float* __restrict__ feats,
                      float* __restrict__ out_pts,
                      int* __restrict__ idx_out,
                      float* __restrict__ trans, int M, int do_trans) {
  __shared__ Smem sm;
  const int t = threadIdx.x;

  if (blockIdx.x >= BB) {
    // ---------------- transpose path ----------------
    if (!do_trans) return;
    for (int tileId = blockIdx.x - BB; tileId < NTILES; tileId += TBLOCKS) {
      int b  = tileId / ((CC / 64) * (NN / 64));
      int r  = tileId % ((CC / 64) * (NN / 64));
      int ct = r / (NN / 64);           // c-tile 0..3
      int nt = r % (NN / 64);           // n-tile 0..127
      const float* src = feats + ((size_t)b * CC + ct * 64) * NN + nt * 64;
      float* dst = trans + ((size_t)b * NN + nt * 64) * CC + ct * 64;
#pragma unroll
      for (int i = 0; i < 2; ++i) {     // 1024 float4 loads / 512 threads
        int f = t + i * NT;
        int c = f >> 4, n4 = f & 15;
        float4 v = *(const float4*)(src + (size_t)c * NN + n4 * 4);
        sm.t.tile[c][n4 * 4 + 0] = v.x;
        sm.t.tile[c][n4 * 4 + 1] = v.y;
        sm.t.tile[c][n4 * 4 + 2] = v.z;
        sm.t.tile[c][n4 * 4 + 3] = v.w;
      }
      __syncthreads();
#pragma unroll
      for (int i = 0; i < 2; ++i) {
        int f = t + i * NT;
        int n = f >> 4, c4 = f & 15;
        float4 o;
        o.x = sm.t.tile[c4 * 4 + 0][n];
        o.y = sm.t.tile[c4 * 4 + 1][n];
        o.z = sm.t.tile[c4 * 4 + 2][n];
        o.w = sm.t.tile[c4 * 4 + 3][n];
        *(float4*)(dst + (size_t)n * CC + c4 * 4) = o;
      }
      __syncthreads();                  // tile reuse across grid-stride iters
    }
    return;
  }

  // ---------------- FPS path ----------------
  const int b = blockIdx.x;
  const int wave = t >> 6;
  const int lane = t & 63;
  const float* base = pts + (size_t)b * 3 * NN;   // [3][N] for this batch

  v2f px2[NPAIR], py2[NPAIR], pz2[NPAIR];
  v2u dist2[NPAIR];
  const uu INIT = __float_as_uint(1e10f);         // matches jnp.full(1e10)
#pragma unroll
  for (int j = 0; j < NPAIR; ++j) {
    int n0 = t + (2 * j) * NT;                    // coalesced loads
    int n1 = t + (2 * j + 1) * NT;
    float x0 = base[n0], y0 = base[NN + n0], z0 = base[2 * NN + n0];
    float x1 = base[n1], y1 = base[NN + n1], z1 = base[2 * NN + n1];
    px2[j] = (v2f){x0, x1};
    py2[j] = (v2f){y0, y1};
    pz2[j] = (v2f){z0, z1};
    sm.f.px[n0] = x0; sm.f.py[n0] = y0; sm.f.pz[n0] = z0;
    sm.f.px[n1] = x1; sm.f.py[n1] = y1; sm.f.pz[n1] = z1;
    dist2[j] = (v2u){INIT, INIT};
  }

  // ---- centroid (one-time; latency irrelevant; standard barriers OK) ----
  float sx = 0.f, sy = 0.f, sz = 0.f;
#pragma unroll
  for (int j = 0; j < NPAIR; ++j) {
    sx += px2[j].x; sx += px2[j].y;
    sy += py2[j].x; sy += py2[j].y;
    sz += pz2[j].x; sz += pz2[j].y;
  }
#pragma unroll
  for (int off = 32; off > 0; off >>= 1) {
    sx += __shfl_xor(sx, off);
    sy += __shfl_xor(sy, off);
    sz += __shfl_xor(sz, off);
  }
  if (lane == 0) { sm.f.red[wave][0] = sx; sm.f.red[wave][1] = sy; sm.f.red[wave][2] = sz; }
  __syncthreads();    // also covers coord-mirror staging writes
  if (t == 0) {
    float gx = 0.f, gy = 0.f, gz = 0.f;
    for (int w = 0; w < NWAVES; ++w) { gx += sm.f.red[w][0]; gy += sm.f.red[w][1]; gz += sm.f.red[w][2]; }
    sm.f.ctr[0] = gx / NN; sm.f.ctr[1] = gy / NN; sm.f.ctr[2] = gz / NN;  // /8192 exact
  }
  __syncthreads();
  const float ctx = sm.f.ctr[0], cty = sm.f.ctr[1], ctz = sm.f.ctr[2];

  int ep = 0;   // key epoch (parity double-buffer -> one barrier per iter)
  int ci;

  // Tail: u64 key wave reduce via DPP (VALU only), lane-63 write, ONE
  // lgkm-only barrier, then a spread b64 read (lane reads key[lane&7];
  // conflict-free) + 3 DPP steps so every lane holds the block max.
  auto reduce_tail = [&](uu v, int bk) {
    ull key = ((ull)v << 32) | (uu)(~(t + (bk << 9)));   // bk*NT, NT=512
    key = wave_max63(key);
    ep ^= 1;
    if (lane == 63) sm.f.key[ep][wave] = key;
    LDS_BARRIER();                     // lgkmcnt-only: no global-store drain
    ull kk = sm.f.key[ep][lane & 7];   // spread ds_read_b64
    kk = dpp_max64<0xB1>(kk);          // xor1 within 8-key group
    kk = dpp_max64<0x4E>(kk);          // xor2
    kk = dpp_max64<0x124>(kk);         // row_ror:4 -> completes all-8 max
    ci = (int)~(uu)kk;
  };

  // ---- initial farthest = argmax of dist-to-centroid (no dist update) ----
  {
    v2f c2x = {ctx, ctx}, c2y = {cty, cty}, c2z = {ctz, ctz};
    v2u nd2[NPAIR];
    uu v = 0u;
#pragma unroll
    for (int j = 0; j < NPAIR; ++j) {
      v2f dx = pk_sub(px2[j], c2x);
      v2f dy = pk_sub(py2[j], c2y);
      v2f dz = pk_sub(pz2[j], c2z);
      // exact numpy order: ((dx*dx + dy*dy) + dz*dz), no FMA
      v2f d = pk_add(pk_add(pk_mul(dx, dx), pk_mul(dy, dy)), pk_mul(dz, dz));
      v2u du = (v2u){__float_as_uint(d.x), __float_as_uint(d.y)};
      nd2[j] = du;
      v = umax2(v, umax2(du.x, du.y));           // v_max3_u32
    }
    int bk = 0;
#pragma unroll
    for (int k = PPT - 1; k >= 0; --k) {         // descending: keeps smallest k
      uu ndk = (k & 1) ? nd2[k >> 1].y : nd2[k >> 1].x;
      if (ndk == v) bk = k;                      // first-occurrence tie-break
    }
    reduce_tail(v, bk);
  }

  // ---- FPS main loop ----
  for (int m = 0; m < M; ++m) {
    // winner coords: 3x b32 same-address broadcast (conflict-free)
    float cx = sm.f.px[ci], cy = sm.f.py[ci], cz = sm.f.pz[ci];
    if (t == 0) {
      idx_out[b * M + m] = ci;
      size_t o = ((size_t)b * M + m) * 3;
      out_pts[o] = cx; out_pts[o + 1] = cy; out_pts[o + 2] = cz;
    }
    if (m == M - 1) break;

    v2f c2x = {cx, cx}, c2y = {cy, cy}, c2z = {cz, cz};
    v2u nd2[NPAIR];
    uu v = 0u;
#pragma unroll
    for (int j = 0; j < NPAIR; ++j) {
      v2f dx = pk_sub(px2[j], c2x);
      v2f dy = pk_sub(py2[j], c2y);
      v2f dz = pk_sub(pz2[j], c2z);
      v2f d = pk_add(pk_add(pk_mul(dx, dx), pk_mul(dy, dy)), pk_mul(dz, dz));
      // dists >= 0 -> u32 min/max on the bits == f32 min/max
      v2u nd;
      nd.x = umin2(dist2[j].x, __float_as_uint(d.x));
      nd.y = umin2(dist2[j].y, __float_as_uint(d.y));
      dist2[j] = nd;
      nd2[j] = nd;
      v = umax2(v, umax2(nd.x, nd.y));           // v_max3_u32 chain
    }
    int bk = 0;
#pragma unroll
    for (int k = PPT - 1; k >= 0; --k) {
      uu ndk = (k & 1) ? nd2[k >> 1].y : nd2[k >> 1].x;
      if (ndk == v) bk = k;
    }
    reduce_tail(v, bk);
  }
}

// Gather from transposed features: fully coalesced float4 both sides.
__global__ __launch_bounds__(256)
void gather_t_kernel(const float* __restrict__ trans,
                     const int* __restrict__ idx,
                     float* __restrict__ out_f, int M) {
  int gm = blockIdx.x * 4 + (threadIdx.x >> 6);
  if (gm >= BB * M) return;
  int lane = threadIdx.x & 63;
  int b = gm / M;
  int n = idx[gm];
  float4 v = *(const float4*)(trans + ((size_t)b * NN + n) * CC + lane * 4);
  *(float4*)(out_f + (size_t)gm * CC + lane * 4) = v;
}

// Fallback gather (ws too small for transpose): scattered reads, L2/L3-bound.
__global__ __launch_bounds__(CC)
void gather_kernel(const float* __restrict__ feats, const int* __restrict__ idx,
                   float* __restrict__ out_f, int M) {
  const int bm = blockIdx.x;
  const int b = bm / M;
  const int n = idx[bm];
  const int c = threadIdx.x;
  out_f[(size_t)bm * CC + c] = feats[((size_t)b * CC + c) * NN + n];
}

extern "C" void kernel_launch(void* const* d_in, const int* in_sizes, int n_in,
                              void* d_out, int out_size, void* d_ws, size_t ws_size,
                              hipStream_t stream) {
  const float* points = (const float*)d_in[0];   // [B,3,N] f32
  const float* feats  = (const float*)d_in[1];   // [B,C,N] f32
  // out_size = B*M*3 + B*M*C = M * B * (3+C)
  int M = out_size / (BB * (3 + CC));            // = 2048
  if (M <= 0) M = 1;

  float* out_pts = (float*)d_out;                        // [B,M,3]
  float* out_f   = (float*)d_out + (size_t)BB * M * 3;   // [B,M,C]

  int* idx_ws = (int*)d_ws;                              // B*M ints
  size_t idx_bytes = (((size_t)BB * M * sizeof(int)) + 255) & ~(size_t)255;
  size_t trans_bytes = (size_t)BB * NN * CC * sizeof(float);   // 134.2 MB
  bool use_t = (ws_size >= idx_bytes + trans_bytes);
  float* trans = (float*)((char*)d_ws + idx_bytes);

  int grid = use_t ? (BB + TBLOCKS) : BB;
  fps_fused_kernel<<<dim3(grid), dim3(NT), 0, stream>>>(
      points, feats, out_pts, idx_ws, trans, M, use_t ? 1 : 0);

  if (use_t) {
    gather_t_kernel<<<dim3((BB * M + 3) / 4), dim3(256), 0, stream>>>(
        trans, idx_ws, out_f, M);
  } else {
    gather_kernel<<<dim3(BB * M), dim3(CC), 0, stream>>>(feats, idx_ws, out_f, M);
  }
}